// Round 1
// baseline (223.718 us; speedup 1.0000x reference)
//
#include <hip/hip_runtime.h>
#include <hip/hip_bf16.h>

// Problem constants
#define VOCAB 50000
#define ED    300
#define NT    16
#define BB    64
#define SS    512

// ---------------------------------------------------------------------------
// Kernel 1: text_lens[b] = sum(text[b,:] != 0). Writes float to d_out and int
// to workspace (crf kernel needs the int form).
// ---------------------------------------------------------------------------
__global__ __launch_bounds__(64) void lens_kernel(const int* __restrict__ text,
                                                  float* __restrict__ out_lens_f,
                                                  int* __restrict__ ws_lens) {
  const int b = blockIdx.x;
  const int t = threadIdx.x;
  const int* row = text + b * SS;
  int cnt = 0;
#pragma unroll
  for (int k = 0; k < SS / 64; ++k) cnt += (row[t + 64 * k] != 0) ? 1 : 0;
  for (int off = 32; off > 0; off >>= 1) cnt += __shfl_xor(cnt, off, 64);
  if (t == 0) {
    out_lens_f[b] = (float)cnt;
    ws_lens[b] = cnt;
  }
}

// ---------------------------------------------------------------------------
// Kernel 2: probs[b,s,:] = emb[text[b,s]] @ W + bias
// 16 rows per block, 256 threads = (16 rows x 16 tags).
// W transposed into LDS (stride 308 to avoid bank aliasing); emb rows staged
// as float4. Inner loop: 2 x ds_read_b128 + 4 FMA per 4 dims.
// ---------------------------------------------------------------------------
#define WSTR 308  // padded row stride (floats); 308*4 bytes is 16B aligned

__global__ __launch_bounds__(256) void probs_kernel(const int* __restrict__ text,
                                                    const float* __restrict__ emb,
                                                    const float* __restrict__ W,
                                                    const float* __restrict__ bias,
                                                    float* __restrict__ out_probs) {
  __shared__ float wt[NT * WSTR];   // wt[t*WSTR + d] = W[d*16 + t]
  __shared__ float es[16 * WSTR];   // es[r*WSTR + d] = emb[token[r]*300 + d]
  __shared__ int tok[16];

  const int tid = threadIdx.x;
  const int row0 = blockIdx.x * 16;

  for (int e = tid; e < ED * NT; e += 256) {
    int d = e >> 4, t = e & 15;
    wt[t * WSTR + d] = W[e];
  }
  if (tid < 16) tok[tid] = text[row0 + tid];
  __syncthreads();

  // stage 16 embedding rows: 16 x 75 float4
  for (int f = tid; f < 16 * 75; f += 256) {
    int r = f / 75, c = f - r * 75;
    const float4* src = (const float4*)(emb + (size_t)tok[r] * ED);
    ((float4*)(es + r * WSTR))[c] = src[c];
  }
  __syncthreads();

  const int r = tid >> 4, t = tid & 15;
  const float4* e4 = (const float4*)(es + r * WSTR);
  const float4* w4 = (const float4*)(wt + t * WSTR);
  float4 acc = make_float4(0.f, 0.f, 0.f, 0.f);
#pragma unroll 5
  for (int c = 0; c < 75; ++c) {
    float4 a = e4[c], w = w4[c];
    acc.x = fmaf(a.x, w.x, acc.x);
    acc.y = fmaf(a.y, w.y, acc.y);
    acc.z = fmaf(a.z, w.z, acc.z);
    acc.w = fmaf(a.w, w.w, acc.w);
  }
  float dot = (acc.x + acc.y) + (acc.z + acc.w) + bias[t];
  out_probs[(size_t)(row0 + r) * NT + t] = dot;
}

// ---------------------------------------------------------------------------
// DPP helpers. All controls used are involutions (quad_perm xor patterns and
// mirrors) -> no rotate-direction ambiguity.
//   0xB1 = quad_perm [1,0,3,2]  (lane ^= 1)
//   0x4E = quad_perm [2,3,0,1]  (lane ^= 2)
//   0x1B = quad_perm [3,2,1,0]  (lane ^= 3)
//   0x141 = row_half_mirror     (lane ^= 7, within 8)
//   0x140 = row_mirror          (lane ^= 15, within 16)
// ---------------------------------------------------------------------------
template <int CTRL>
__device__ __forceinline__ float dppmov(float x) {
  return __int_as_float(
      __builtin_amdgcn_update_dpp(0, __float_as_int(x), CTRL, 0xF, 0xF, false));
}

// All lanes of a 16-lane row end with lam[k] = g_{j^k} (j = lane&15).
__device__ __forceinline__ void allgather16(float g, float lam[16]) {
  lam[0] = g;
  lam[1] = dppmov<0xB1>(g);
  lam[2] = dppmov<0x4E>(g);
  lam[3] = dppmov<0x1B>(g);
  float h = dppmov<0x141>(g);   // j^7
  lam[7] = h;
  lam[6] = dppmov<0xB1>(h);
  lam[5] = dppmov<0x4E>(h);
  lam[4] = dppmov<0x1B>(h);
  float m = dppmov<0x140>(g);   // j^15
  lam[15] = m;
  lam[14] = dppmov<0xB1>(m);
  lam[13] = dppmov<0x4E>(m);
  lam[12] = dppmov<0x1B>(m);
  float c = dppmov<0x141>(m);   // j^8
  lam[8] = c;
  lam[9]  = dppmov<0xB1>(c);
  lam[10] = dppmov<0x4E>(c);
  lam[11] = dppmov<0x1B>(c);
}

// ---------------------------------------------------------------------------
// Kernel 3: CRF log-likelihood. 64 threads/block = 4 batches x 16 lanes.
// Forward scan in exp space:
//   alpha_j = K*ln2... tracked as: alpha_j = ln(lam-set) + K2*ln2
//   step: g_j = (sum_i gamma_i * exp(trans_ij)) * exp(emit_j)
// lam[] holds all 16 gammas replicated per lane in j^k order; E[] is
// exp(trans) pre-permuted to match. Max-renormalize every 4 steps.
// ---------------------------------------------------------------------------
__global__ __launch_bounds__(64) void crf_kernel(const int* __restrict__ tags,
                                                 const float* __restrict__ trans,
                                                 const float* __restrict__ probs,
                                                 const int* __restrict__ ws_lens,
                                                 float* __restrict__ out_ll) {
  __shared__ float tr[256];
  const int tid = threadIdx.x;
  const int grp = tid >> 4;  // 0..3
  const int j = tid & 15;
  const int b = blockIdx.x * 4 + grp;

  for (int e = tid; e < 256; e += 64) tr[e] = trans[e];
  __syncthreads();

  const int len = ws_lens[b];
  const int* tg = tags + b * SS;
  const float* pb = probs + (size_t)b * SS * NT;

  // ---- phase A: unary + binary scores ----
  float sc = 0.f;
  for (int s = j; s < SS; s += 16) {
    if (s < len) {
      int t1 = tg[s];
      sc += pb[s * NT + t1];
      if (s >= 1) sc += tr[tg[s - 1] * 16 + t1];
    }
  }
  // butterfly sum over the 16-lane row (xor masks 1,2,7,15 form a chain)
  sc += dppmov<0xB1>(sc);
  sc += dppmov<0x4E>(sc);
  sc += dppmov<0x141>(sc);
  sc += dppmov<0x140>(sc);

  // ---- E columns, permuted to j^k order ----
  float E[16];
#pragma unroll
  for (int k = 0; k < 16; ++k) E[k] = __expf(tr[((j ^ k) << 4) + j]);

  // ---- init: lam[k] = exp(probs[b,0,j^k]) ----
  float lam[16];
  {
    float g0 = __expf(pb[j]);
    allgather16(g0, lam);
  }
  float K2 = 0.f;  // accumulated log2 scale

  // prefetch emissions for steps 1..4
  float raw[4];
#pragma unroll
  for (int c = 0; c < 4; ++c) raw[c] = pb[(1 + c) * NT + j];

  for (int blk = 0; blk < 128; ++blk) {
    const int s0 = 1 + blk * 4;
    float pe[4];
#pragma unroll
    for (int c = 0; c < 4; ++c) pe[c] = __expf(raw[c]);
    if (blk < 127) {
#pragma unroll
      for (int c = 0; c < 4; ++c) raw[c] = pb[(s0 + 4 + c) * NT + j];
    }
#pragma unroll
    for (int c = 0; c < 4; ++c) {
      const int s = s0 + c;
      if (s < len) {  // uniform per 16-lane row; s=512 tail auto-masked
        float p0 = fmaf(lam[0], E[0], fmaf(lam[4], E[4], fmaf(lam[8], E[8], lam[12] * E[12])));
        float p1 = fmaf(lam[1], E[1], fmaf(lam[5], E[5], fmaf(lam[9], E[9], lam[13] * E[13])));
        float p2 = fmaf(lam[2], E[2], fmaf(lam[6], E[6], fmaf(lam[10], E[10], lam[14] * E[14])));
        float p3 = fmaf(lam[3], E[3], fmaf(lam[7], E[7], fmaf(lam[11], E[11], lam[15] * E[15])));
        float g = ((p0 + p1) + (p2 + p3)) * pe[c];
        allgather16(g, lam);
      }
    }
    // renormalize (semantically a no-op: folded into K2; safe on frozen rows)
    float mx = lam[0];
#pragma unroll
    for (int k = 1; k < 16; ++k) mx = fmaxf(mx, lam[k]);
    float rr = 1.0f / mx;
    K2 -= __log2f(rr);
#pragma unroll
    for (int k = 0; k < 16; ++k) lam[k] *= rr;
  }

  float sum = ((lam[0] + lam[1]) + (lam[2] + lam[3])) +
              ((lam[4] + lam[5]) + (lam[6] + lam[7])) +
              ((lam[8] + lam[9]) + (lam[10] + lam[11])) +
              ((lam[12] + lam[13]) + (lam[14] + lam[15]));
  float log_norm = 0.6931471805599453f * (K2 + __log2f(sum));
  if (j == 0) out_ll[b] = sc - log_norm;
}

// ---------------------------------------------------------------------------
extern "C" void kernel_launch(void* const* d_in, const int* in_sizes, int n_in,
                              void* d_out, int out_size, void* d_ws, size_t ws_size,
                              hipStream_t stream) {
  const int* text = (const int*)d_in[0];
  const int* tags = (const int*)d_in[1];
  const float* emb = (const float*)d_in[2];
  const float* W = (const float*)d_in[3];
  const float* bias = (const float*)d_in[4];
  const float* trans = (const float*)d_in[5];

  float* out = (float*)d_out;
  float* out_probs = out;                       // 64*512*16
  float* out_lens = out + BB * SS * NT;         // 64
  float* out_ll = out + BB * SS * NT + BB;      // 64
  int* ws_lens = (int*)d_ws;

  lens_kernel<<<BB, 64, 0, stream>>>(text, out_lens, ws_lens);
  probs_kernel<<<(BB * SS) / 16, 256, 0, stream>>>(text, emb, W, bias, out_probs);
  crf_kernel<<<BB / 4, 64, 0, stream>>>(tags, trans, out_probs, ws_lens, out_ll);
}

// Round 2
// 207.687 us; speedup vs baseline: 1.0772x; 1.0772x over previous
//
#include <hip/hip_runtime.h>
#include <hip/hip_bf16.h>

// Problem constants
#define VOCAB 50000
#define ED    300
#define NT    16
#define BB    64
#define SS    512

// ---------------------------------------------------------------------------
// Kernel 1: text_lens[b] = sum(text[b,:] != 0). Float copy to d_out, int copy
// to workspace for the crf kernel.
// ---------------------------------------------------------------------------
__global__ __launch_bounds__(64) void lens_kernel(const int* __restrict__ text,
                                                  float* __restrict__ out_lens_f,
                                                  int* __restrict__ ws_lens) {
  const int b = blockIdx.x;
  const int t = threadIdx.x;
  const int* row = text + b * SS;
  int cnt = 0;
#pragma unroll
  for (int k = 0; k < SS / 64; ++k) cnt += (row[t + 64 * k] != 0) ? 1 : 0;
  for (int off = 32; off > 0; off >>= 1) cnt += __shfl_xor(cnt, off, 64);
  if (t == 0) {
    out_lens_f[b] = (float)cnt;
    ws_lens[b] = cnt;
  }
}

// ---------------------------------------------------------------------------
// Kernel 2: probs[row,:] = emb[text[row]] @ W + bias.
// Thread = one row; acc[16] in VGPRs. emb row streamed as float4 with a
// 2-group register-prefetch pipeline (groups of 5 float4 = 20 dims; distance
// ~640 cyc covers L2/HBM latency). W addresses are wave-uniform -> s_load,
// W values ride in SGPRs. No LDS, no barriers.
// ---------------------------------------------------------------------------
__global__ __launch_bounds__(64) void probs_kernel(const int* __restrict__ text,
                                                   const float* __restrict__ emb,
                                                   const float* __restrict__ W,
                                                   const float* __restrict__ bias,
                                                   float* __restrict__ out_probs) {
  const int row = blockIdx.x * 64 + threadIdx.x;
  const int tok = text[row];
  const float4* erow = (const float4*)(emb + (size_t)tok * ED);

  float acc[NT];
#pragma unroll
  for (int t = 0; t < NT; ++t) acc[t] = bias[t];

  float4 A[5], B[5];
#pragma unroll
  for (int i = 0; i < 5; ++i) A[i] = erow[i];
#pragma unroll
  for (int i = 0; i < 5; ++i) B[i] = erow[5 + i];

#pragma unroll 3
  for (int g = 0; g < 15; ++g) {
    float4 C[5];
    {
      // prefetch group g+2 (clamped in-bounds; redundant loads for g>=13)
      int base = (g + 2) * 5;
      if (base > 70) base = 70;
#pragma unroll
      for (int i = 0; i < 5; ++i) C[i] = erow[base + i];
    }
    const int d0 = g * 20;
#pragma unroll
    for (int i = 0; i < 5; ++i) {
      const float e0 = A[i].x, e1 = A[i].y, e2 = A[i].z, e3 = A[i].w;
      const float* w0 = W + (size_t)(d0 + 4 * i) * NT;  // uniform address
#pragma unroll
      for (int t = 0; t < NT; ++t) acc[t] = fmaf(e0, w0[t], acc[t]);
#pragma unroll
      for (int t = 0; t < NT; ++t) acc[t] = fmaf(e1, w0[NT + t], acc[t]);
#pragma unroll
      for (int t = 0; t < NT; ++t) acc[t] = fmaf(e2, w0[2 * NT + t], acc[t]);
#pragma unroll
      for (int t = 0; t < NT; ++t) acc[t] = fmaf(e3, w0[3 * NT + t], acc[t]);
    }
#pragma unroll
    for (int i = 0; i < 5; ++i) { A[i] = B[i]; B[i] = C[i]; }
  }

  float4* orow = (float4*)(out_probs + (size_t)row * NT);
#pragma unroll
  for (int q = 0; q < 4; ++q)
    orow[q] = make_float4(acc[4 * q], acc[4 * q + 1], acc[4 * q + 2], acc[4 * q + 3]);
}

// ---------------------------------------------------------------------------
// DPP helpers (HW-verified in round 1). All controls are involutions:
//   0xB1 quad_perm lane^1, 0x4E lane^2, 0x1B lane^3,
//   0x141 row_half_mirror lane^7, 0x140 row_mirror lane^15.
// ---------------------------------------------------------------------------
template <int CTRL>
__device__ __forceinline__ float dppmov(float x) {
  return __int_as_float(
      __builtin_amdgcn_update_dpp(0, __float_as_int(x), CTRL, 0xF, 0xF, false));
}

// All lanes of a 16-lane row end with lam[k] = g_{j^k} (j = lane&15).
__device__ __forceinline__ void allgather16(float g, float lam[16]) {
  lam[0] = g;
  lam[1] = dppmov<0xB1>(g);
  lam[2] = dppmov<0x4E>(g);
  lam[3] = dppmov<0x1B>(g);
  float h = dppmov<0x141>(g);   // j^7
  lam[7] = h;
  lam[6] = dppmov<0xB1>(h);
  lam[5] = dppmov<0x4E>(h);
  lam[4] = dppmov<0x1B>(h);
  float m = dppmov<0x140>(g);   // j^15
  lam[15] = m;
  lam[14] = dppmov<0xB1>(m);
  lam[13] = dppmov<0x4E>(m);
  lam[12] = dppmov<0x1B>(m);
  float c = dppmov<0x141>(m);   // j^8
  lam[8] = c;
  lam[9]  = dppmov<0xB1>(c);
  lam[10] = dppmov<0x4E>(c);
  lam[11] = dppmov<0x1B>(c);
}

// ---------------------------------------------------------------------------
// Kernel 3: CRF log-likelihood. ONE batch per block, 64 threads.
// All of this batch's probs (32KB) + tags + trans staged to LDS up front, so
// the 511-step serial scan never touches global memory. The 4 quads of the
// wave compute the scan redundantly (j = lane&15) -> no divergence, and the
// s<len branch is wave-uniform (scalar branch).
// ---------------------------------------------------------------------------
__global__ __launch_bounds__(64) void crf_kernel(const int* __restrict__ tags,
                                                 const float* __restrict__ trans,
                                                 const float* __restrict__ probs,
                                                 const int* __restrict__ ws_lens,
                                                 float* __restrict__ out_ll) {
  __shared__ float ps[SS * NT];  // 32 KB: this batch's probs
  __shared__ int tgs[SS];        // 2 KB
  __shared__ float trs[256];     // 1 KB

  const int tid = threadIdx.x;
  const int j = tid & 15;
  const int b = blockIdx.x;

  // ---- stage to LDS (coalesced) ----
  {
    const float4* p4 = (const float4*)(probs + (size_t)b * SS * NT);
    float4* l4 = (float4*)ps;
#pragma unroll
    for (int i = 0; i < 32; ++i) l4[tid + 64 * i] = p4[tid + 64 * i];
    const int4* t4 = (const int4*)(tags + b * SS);
    int4* lt = (int4*)tgs;
#pragma unroll
    for (int i = 0; i < 2; ++i) lt[tid + 64 * i] = t4[tid + 64 * i];
    for (int i = tid; i < 256; i += 64) trs[i] = trans[i];
  }
  __syncthreads();

  const int len = ws_lens[b];

  // ---- phase A: unary + binary scores (all 64 lanes) ----
  float sc = 0.f;
#pragma unroll
  for (int it = 0; it < SS / 64; ++it) {
    const int s = tid + 64 * it;
    if (s < len) {
      int t1 = tgs[s];
      sc += ps[s * NT + t1];
      if (s >= 1) sc += trs[tgs[s - 1] * 16 + t1];
    }
  }
  for (int off = 32; off > 0; off >>= 1) sc += __shfl_xor(sc, off, 64);

  // ---- E columns in j^k order ----
  float E[16];
#pragma unroll
  for (int k = 0; k < 16; ++k) E[k] = __expf(trs[((j ^ k) << 4) + j]);

  // ---- init lam from step 0 ----
  float lam[16];
  allgather16(__expf(ps[j]), lam);
  float K2 = 0.f;  // accumulated log2 scale

  // prefetch emissions for steps 1..8
  float raw[8];
#pragma unroll
  for (int c = 0; c < 8; ++c) raw[c] = ps[(1 + c) * NT + j];

  for (int blk = 0; blk < 64; ++blk) {
    float pe[8];
#pragma unroll
    for (int c = 0; c < 8; ++c) pe[c] = __expf(raw[c]);
    if (blk < 63) {
#pragma unroll
      for (int c = 0; c < 8; ++c) {
        int s = blk * 8 + 9 + c;
        if (s > 511) s = 511;  // clamp (value never used past len)
        raw[c] = ps[s * NT + j];
      }
    }
#pragma unroll
    for (int c = 0; c < 8; ++c) {
      const int s = blk * 8 + 1 + c;
      if (s < len) {  // wave-uniform
        float p0 = fmaf(lam[0], E[0], fmaf(lam[4], E[4], fmaf(lam[8], E[8], lam[12] * E[12])));
        float p1 = fmaf(lam[1], E[1], fmaf(lam[5], E[5], fmaf(lam[9], E[9], lam[13] * E[13])));
        float p2 = fmaf(lam[2], E[2], fmaf(lam[6], E[6], fmaf(lam[10], E[10], lam[14] * E[14])));
        float p3 = fmaf(lam[3], E[3], fmaf(lam[7], E[7], fmaf(lam[11], E[11], lam[15] * E[15])));
        float g = ((p0 + p1) + (p2 + p3)) * pe[c];
        allgather16(g, lam);
      }
    }
    // renormalize every 8 steps (growth <= ~2^45, fp32-safe); exact no-op in
    // the tracked value: K2 compensates, frozen rows unaffected.
    float mx = lam[0];
#pragma unroll
    for (int k = 1; k < 16; ++k) mx = fmaxf(mx, lam[k]);
    float rr = 1.0f / mx;
    K2 -= __log2f(rr);
#pragma unroll
    for (int k = 0; k < 16; ++k) lam[k] *= rr;
  }

  float sum = ((lam[0] + lam[1]) + (lam[2] + lam[3])) +
              ((lam[4] + lam[5]) + (lam[6] + lam[7])) +
              ((lam[8] + lam[9]) + (lam[10] + lam[11])) +
              ((lam[12] + lam[13]) + (lam[14] + lam[15]));
  float log_norm = 0.6931471805599453f * (K2 + __log2f(sum));
  if (tid == 0) out_ll[b] = sc - log_norm;
}

// ---------------------------------------------------------------------------
extern "C" void kernel_launch(void* const* d_in, const int* in_sizes, int n_in,
                              void* d_out, int out_size, void* d_ws, size_t ws_size,
                              hipStream_t stream) {
  const int* text = (const int*)d_in[0];
  const int* tags = (const int*)d_in[1];
  const float* emb = (const float*)d_in[2];
  const float* W = (const float*)d_in[3];
  const float* bias = (const float*)d_in[4];
  const float* trans = (const float*)d_in[5];

  float* out = (float*)d_out;
  float* out_probs = out;                   // 64*512*16
  float* out_lens = out + BB * SS * NT;     // 64
  float* out_ll = out + BB * SS * NT + BB;  // 64
  int* ws_lens = (int*)d_ws;

  lens_kernel<<<BB, 64, 0, stream>>>(text, out_lens, ws_lens);
  probs_kernel<<<(BB * SS) / 64, 64, 0, stream>>>(text, emb, W, bias, out_probs);
  crf_kernel<<<BB, 64, 0, stream>>>(tags, trans, out_probs, ws_lens, out_ll);
}

// Round 3
// 169.829 us; speedup vs baseline: 1.3173x; 1.2229x over previous
//
#include <hip/hip_runtime.h>
#include <hip/hip_bf16.h>

// Problem constants
#define VOCAB 50000
#define ED    300
#define NT    16
#define BB    64
#define SS    512

#define LOG2E 1.4426950408889634f
#define LN2   0.6931471805599453f

// ---------------------------------------------------------------------------
// Kernel 1: probs[row,:] = emb[text[row]] @ W + bias.
// Lane layout within a wave: r = lane>>4 (4 rows), t = lane&15 (16 tags).
//  - emb float4 loads: 16 lanes share an address -> 4 cache lines/instr.
//  - W loads: lanes span 16 consecutive floats = exactly 1 64B line/instr,
//    W (19.2 KB) stays L1-resident.
//  - store: 64 lanes write 256 B contiguous.
// 2048 blocks x 256 thr = 8 waves/SIMD -> latency hidden by TLP.
// ---------------------------------------------------------------------------
__global__ __launch_bounds__(256) void probs_kernel(const int* __restrict__ text,
                                                    const float* __restrict__ emb,
                                                    const float* __restrict__ W,
                                                    const float* __restrict__ bias,
                                                    float* __restrict__ out_probs) {
  const int tid = threadIdx.x;
  const int lane = tid & 63, wave = tid >> 6;
  const int r = lane >> 4, t = lane & 15;
  const int row = blockIdx.x * 16 + wave * 4 + r;

  const int tok = text[row];
  const float4* erow = (const float4*)(emb + (size_t)tok * ED);

  float acc = bias[t];
#pragma unroll 5
  for (int c = 0; c < 75; ++c) {
    float4 e = erow[c];
    const float* wp = W + (size_t)(4 * c) * NT + t;
    acc = fmaf(e.x, wp[0],      acc);
    acc = fmaf(e.y, wp[NT],     acc);
    acc = fmaf(e.z, wp[2 * NT], acc);
    acc = fmaf(e.w, wp[3 * NT], acc);
  }
  out_probs[(size_t)row * NT + t] = acc;
}

// ---------------------------------------------------------------------------
// DPP helpers (controls HW-verified rounds 1-2). old = src (involutions, all
// lanes active -> old never observed; avoids the zero-materializing v_mov).
//   0xB1 quad_perm lane^1, 0x4E lane^2, 0x1B lane^3,
//   0x141 row_half_mirror lane^7, 0x140 row_mirror lane^15.
// ---------------------------------------------------------------------------
template <int CTRL>
__device__ __forceinline__ float dppmov(float x) {
  int xi = __float_as_int(x);
  return __int_as_float(
      __builtin_amdgcn_update_dpp(xi, xi, CTRL, 0xF, 0xF, false));
}

// ---------------------------------------------------------------------------
// One CRF forward step, fused DPP matvec. Lane j (within each 16-lane row)
// holds alpha_j (linear domain, scaled). Computes
//   gn_j = (sum_k alpha_{j^k} * E[k]_j) * pe_j
// with E[k]_j = exp(trans[j^k, j]). 4 partial chains:
//   chain A (src g        = a_{j^0}):  k = 0,1,2,3   (quad_perm xors)
//   chain B (src h=^7(g)  = a_{j^7}):  k = 7,6,5,4
//   chain C (src m=^15(g) = a_{j^15}): k = 15,14,13,12
//   chain D (src c=^7(m)  = a_{j^8}):  k = 8,9,10,11
// Hazard notes: s_nop 1 covers (compiler writes g just before) -> DPP read;
// every DPP read of h/m/c is >=4 instructions after its write.
// ---------------------------------------------------------------------------
__device__ __forceinline__ float crf_step(float g, float pe, const float E[16]) {
  float gn, h, m, c, a1, a2, a3;
  asm("s_nop 1\n\t"
      "v_mov_b32_dpp %[h], %[g] row_half_mirror row_mask:0xf bank_mask:0xf\n\t"
      "v_mov_b32_dpp %[m], %[g] row_mirror row_mask:0xf bank_mask:0xf\n\t"
      "v_mul_f32 %[gn], %[g], %[e0]\n\t"
      "v_fmac_f32_dpp %[gn], %[g], %[e1] quad_perm:[1,0,3,2] row_mask:0xf bank_mask:0xf\n\t"
      "v_fmac_f32_dpp %[gn], %[g], %[e2] quad_perm:[2,3,0,1] row_mask:0xf bank_mask:0xf\n\t"
      "v_fmac_f32_dpp %[gn], %[g], %[e3] quad_perm:[3,2,1,0] row_mask:0xf bank_mask:0xf\n\t"
      "v_mov_b32_dpp %[c], %[m] row_half_mirror row_mask:0xf bank_mask:0xf\n\t"
      "v_mul_f32 %[a1], %[h], %[e7]\n\t"
      "v_fmac_f32_dpp %[a1], %[h], %[e6] quad_perm:[1,0,3,2] row_mask:0xf bank_mask:0xf\n\t"
      "v_fmac_f32_dpp %[a1], %[h], %[e5] quad_perm:[2,3,0,1] row_mask:0xf bank_mask:0xf\n\t"
      "v_fmac_f32_dpp %[a1], %[h], %[e4] quad_perm:[3,2,1,0] row_mask:0xf bank_mask:0xf\n\t"
      "v_mul_f32 %[a2], %[m], %[e15]\n\t"
      "v_fmac_f32_dpp %[a2], %[m], %[e14] quad_perm:[1,0,3,2] row_mask:0xf bank_mask:0xf\n\t"
      "v_fmac_f32_dpp %[a2], %[m], %[e13] quad_perm:[2,3,0,1] row_mask:0xf bank_mask:0xf\n\t"
      "v_fmac_f32_dpp %[a2], %[m], %[e12] quad_perm:[3,2,1,0] row_mask:0xf bank_mask:0xf\n\t"
      "v_mul_f32 %[a3], %[c], %[e8]\n\t"
      "v_fmac_f32_dpp %[a3], %[c], %[e9] quad_perm:[1,0,3,2] row_mask:0xf bank_mask:0xf\n\t"
      "v_fmac_f32_dpp %[a3], %[c], %[e10] quad_perm:[2,3,0,1] row_mask:0xf bank_mask:0xf\n\t"
      "v_fmac_f32_dpp %[a3], %[c], %[e11] quad_perm:[3,2,1,0] row_mask:0xf bank_mask:0xf\n\t"
      "v_add_f32 %[gn], %[gn], %[a1]\n\t"
      "v_add_f32 %[a2], %[a2], %[a3]\n\t"
      "v_add_f32 %[gn], %[gn], %[a2]\n\t"
      "v_mul_f32 %[gn], %[gn], %[pe]"
      : [gn] "=&v"(gn), [h] "=&v"(h), [m] "=&v"(m), [c] "=&v"(c),
        [a1] "=&v"(a1), [a2] "=&v"(a2), [a3] "=&v"(a3)
      : [g] "v"(g), [pe] "v"(pe),
        [e0] "v"(E[0]), [e1] "v"(E[1]), [e2] "v"(E[2]), [e3] "v"(E[3]),
        [e4] "v"(E[4]), [e5] "v"(E[5]), [e6] "v"(E[6]), [e7] "v"(E[7]),
        [e8] "v"(E[8]), [e9] "v"(E[9]), [e10] "v"(E[10]), [e11] "v"(E[11]),
        [e12] "v"(E[12]), [e13] "v"(E[13]), [e14] "v"(E[14]), [e15] "v"(E[15]));
  return gn;
}

// ---------------------------------------------------------------------------
// Kernel 2: lens + CRF log-likelihood. One batch per block, 64 threads
// (4 redundant 16-lane rows; DPP controls confine to 16-lane rows).
// probs staged to LDS pre-scaled by log2(e) so per-step exp is one v_exp.
// Scan state: single per-lane g (alpha_j, linear) + K2 (log2 scale).
// ---------------------------------------------------------------------------
__global__ __launch_bounds__(64) void crf_kernel(const int* __restrict__ text,
                                                 const int* __restrict__ tags,
                                                 const float* __restrict__ trans,
                                                 const float* __restrict__ probs,
                                                 float* __restrict__ out_lens,
                                                 float* __restrict__ out_ll) {
  __shared__ float lps[SS * NT];  // 32 KB, probs * LOG2E
  __shared__ int tgs[SS];         // 2 KB
  __shared__ float trs[256];      // 1 KB (raw)

  const int tid = threadIdx.x;
  const int j = tid & 15;
  const int b = blockIdx.x;

  // ---- stage (coalesced), pre-scaling probs by log2e ----
  {
    const float4* p4 = (const float4*)(probs + (size_t)b * SS * NT);
    float4* l4 = (float4*)lps;
#pragma unroll
    for (int i = 0; i < 32; ++i) {
      float4 v = p4[tid + 64 * i];
      v.x *= LOG2E; v.y *= LOG2E; v.z *= LOG2E; v.w *= LOG2E;
      l4[tid + 64 * i] = v;
    }
    const int4* t4 = (const int4*)(tags + b * SS);
    int4* lt = (int4*)tgs;
#pragma unroll
    for (int i = 0; i < 2; ++i) lt[tid + 64 * i] = t4[tid + 64 * i];
    for (int i = tid; i < 256; i += 64) trs[i] = trans[i];
  }
  __syncthreads();

  // ---- lens (fused) ----
  const int* tx = text + b * SS;
  int cnt = 0;
#pragma unroll
  for (int k = 0; k < 8; ++k) cnt += (tx[tid + 64 * k] != 0) ? 1 : 0;
  for (int off = 32; off > 0; off >>= 1) cnt += __shfl_xor(cnt, off, 64);
  const int len = cnt;
  if (tid == 0) out_lens[b] = (float)len;

  // ---- phase A: unary (scaled, x ln2 later) + binary scores ----
  float su = 0.f, sb = 0.f;
#pragma unroll
  for (int it = 0; it < 8; ++it) {
    const int s = tid + 64 * it;
    if (s < len) {
      int t1 = tgs[s];
      su += lps[s * NT + t1];
      if (s >= 1) sb += trs[tgs[s - 1] * 16 + t1];
    }
  }
  float sc = fmaf(su, LN2, sb);
  for (int off = 32; off > 0; off >>= 1) sc += __shfl_xor(sc, off, 64);

  // ---- E[k] = exp(trans[j^k, j]) ----
  float E[16];
#pragma unroll
  for (int k = 0; k < 16; ++k) E[k] = __expf(trs[((j ^ k) << 4) + j]);

  // ---- scan init ----
  float g = exp2f(lps[j]);  // exp(probs[b,0,j])
  float K2 = 0.f;

  float raw[16];
#pragma unroll
  for (int c = 0; c < 16; ++c) raw[c] = lps[(1 + c) * NT + j];

  // main: 31 blocks x 16 steps = s in [1,496]
  for (int blk = 0; blk < 31; ++blk) {
#pragma unroll
    for (int c = 0; c < 16; ++c) {
      const int s = 1 + blk * 16 + c;
      float pe = exp2f(raw[c]);
      int spre = s + 16; if (spre > 511) spre = 511;
      raw[c] = lps[spre * NT + j];
      float gn = crf_step(g, pe, E);
      g = (s < len) ? gn : g;
    }
    // renorm every 16 steps (growth <= ~2^90 < 2^127). Exact fold into K2:
    // the same rr multiplies g and enters K2 via log2.
    float mx = g;
    mx = fmaxf(mx, dppmov<0xB1>(mx));
    mx = fmaxf(mx, dppmov<0x4E>(mx));
    mx = fmaxf(mx, dppmov<0x141>(mx));
    mx = fmaxf(mx, dppmov<0x140>(mx));
    float rr = 1.0f / mx;
    K2 -= __log2f(rr);
    g *= rr;
  }
  // tail: s in [497,511] (15 steps; growth <= 2^85, safe)
#pragma unroll
  for (int c = 0; c < 15; ++c) {
    const int s = 497 + c;
    float pe = exp2f(raw[c]);
    float gn = crf_step(g, pe, E);
    g = (s < len) ? gn : g;
  }

  // ---- final: logsumexp across the 16 alphas ----
  float x = g;
  x += dppmov<0xB1>(x);
  x += dppmov<0x4E>(x);
  x += dppmov<0x141>(x);
  x += dppmov<0x140>(x);
  float log_norm = LN2 * (K2 + __log2f(x));
  if (tid == 0) out_ll[b] = sc - log_norm;
}

// ---------------------------------------------------------------------------
extern "C" void kernel_launch(void* const* d_in, const int* in_sizes, int n_in,
                              void* d_out, int out_size, void* d_ws, size_t ws_size,
                              hipStream_t stream) {
  const int* text = (const int*)d_in[0];
  const int* tags = (const int*)d_in[1];
  const float* emb = (const float*)d_in[2];
  const float* W = (const float*)d_in[3];
  const float* bias = (const float*)d_in[4];
  const float* trans = (const float*)d_in[5];

  float* out = (float*)d_out;
  float* out_probs = out;                   // 64*512*16
  float* out_lens = out + BB * SS * NT;     // 64
  float* out_ll = out + BB * SS * NT + BB;  // 64

  probs_kernel<<<(BB * SS) / 16, 256, 0, stream>>>(text, emb, W, bias, out_probs);
  crf_kernel<<<BB, 64, 0, stream>>>(text, tags, trans, out_probs, out_lens, out_ll);
}

// Round 4
// 151.679 us; speedup vs baseline: 1.4749x; 1.1197x over previous
//
#include <hip/hip_runtime.h>
#include <hip/hip_bf16.h>

// Problem constants
#define VOCAB 50000
#define ED    300
#define NT    16
#define BB    64
#define SS    512

#define LOG2E 1.4426950408889634f
#define LN2   0.6931471805599453f

// ---------------------------------------------------------------------------
// Kernel 1: probs[row,:] = emb[text[row]] @ W + bias.
// Lane layout: r = lane>>4 (4 rows/wave), t = lane&15 (16 tags).
// W transposed in LDS (stride 308 floats: bank pattern (t*20+4c)%32 covers all
// 32 banks 2x per 16 lanes -> 2-way aliasing, free). Hot loop: 1 e-float4
// VMEM + 1 ds_read_b128 + 4 FMA. The vmcnt queue holds ONLY e-loads; an
// 8-deep rolling register prefetch keeps ~8 loads/wave in flight to cover the
// ~900cyc HBM-miss latency of the random emb gather.
// ---------------------------------------------------------------------------
#define WSTR 308

__global__ __launch_bounds__(256) void probs_kernel(const int* __restrict__ text,
                                                    const float* __restrict__ emb,
                                                    const float* __restrict__ W,
                                                    const float* __restrict__ bias,
                                                    float* __restrict__ out_probs) {
  __shared__ float wt[NT * WSTR];  // wt[t*WSTR + d] = W[d*16 + t]

  const int tid = threadIdx.x;
  const int lane = tid & 63, wave = tid >> 6;
  const int r = lane >> 4, t = lane & 15;
  const int row = blockIdx.x * 16 + wave * 4 + r;

  // stage W transposed (coalesced global read; 2-way LDS write aliasing)
  for (int e = tid; e < ED * NT; e += 256) {
    int d = e >> 4, tt = e & 15;
    wt[tt * WSTR + d] = W[e];
  }

  const int tok = text[row];
  const float4* erow = (const float4*)(emb + (size_t)tok * ED);
  float acc = bias[t];

  // start the prefetch pipeline before the barrier (global, not LDS)
  float4 A[8];
#pragma unroll
  for (int i = 0; i < 8; ++i) A[i] = erow[i];

  __syncthreads();

  const float4* w4 = (const float4*)(wt + t * WSTR);
#pragma unroll
  for (int c = 0; c < 75; ++c) {
    float4 e = A[c % 8];
    if (c < 67) A[c % 8] = erow[c + 8];
    float4 w = w4[c];
    acc = fmaf(e.x, w.x, acc);
    acc = fmaf(e.y, w.y, acc);
    acc = fmaf(e.z, w.z, acc);
    acc = fmaf(e.w, w.w, acc);
  }
  out_probs[(size_t)row * NT + t] = acc;
}

// ---------------------------------------------------------------------------
// DPP helpers (controls HW-verified rounds 1-3). old = src (involutions, all
// lanes active -> old never observed).
//   0xB1 quad_perm lane^1, 0x4E lane^2, 0x1B lane^3,
//   0x141 row_half_mirror lane^7, 0x140 row_mirror lane^15.
// ---------------------------------------------------------------------------
template <int CTRL>
__device__ __forceinline__ float dppmov(float x) {
  int xi = __float_as_int(x);
  return __int_as_float(
      __builtin_amdgcn_update_dpp(xi, xi, CTRL, 0xF, 0xF, false));
}

// ---------------------------------------------------------------------------
// One CRF forward step, fused DPP matvec (HW-verified round 3).
//   gn_j = (sum_k alpha_{j^k} * E[k]_j) * pe_j,  E[k]_j = exp(trans[j^k, j])
// 4 chains seeded from g, ^7(g), ^15(g), ^7(^15(g)); quad_perm xors inside.
// s_nop 1 covers the (previous-step v_mul writes g) -> DPP-read hazard.
// ---------------------------------------------------------------------------
__device__ __forceinline__ float crf_step(float g, float pe, const float E[16]) {
  float gn, h, m, c, a1, a2, a3;
  asm("s_nop 1\n\t"
      "v_mov_b32_dpp %[h], %[g] row_half_mirror row_mask:0xf bank_mask:0xf\n\t"
      "v_mov_b32_dpp %[m], %[g] row_mirror row_mask:0xf bank_mask:0xf\n\t"
      "v_mul_f32 %[gn], %[g], %[e0]\n\t"
      "v_fmac_f32_dpp %[gn], %[g], %[e1] quad_perm:[1,0,3,2] row_mask:0xf bank_mask:0xf\n\t"
      "v_fmac_f32_dpp %[gn], %[g], %[e2] quad_perm:[2,3,0,1] row_mask:0xf bank_mask:0xf\n\t"
      "v_fmac_f32_dpp %[gn], %[g], %[e3] quad_perm:[3,2,1,0] row_mask:0xf bank_mask:0xf\n\t"
      "v_mov_b32_dpp %[c], %[m] row_half_mirror row_mask:0xf bank_mask:0xf\n\t"
      "v_mul_f32 %[a1], %[h], %[e7]\n\t"
      "v_fmac_f32_dpp %[a1], %[h], %[e6] quad_perm:[1,0,3,2] row_mask:0xf bank_mask:0xf\n\t"
      "v_fmac_f32_dpp %[a1], %[h], %[e5] quad_perm:[2,3,0,1] row_mask:0xf bank_mask:0xf\n\t"
      "v_fmac_f32_dpp %[a1], %[h], %[e4] quad_perm:[3,2,1,0] row_mask:0xf bank_mask:0xf\n\t"
      "v_mul_f32 %[a2], %[m], %[e15]\n\t"
      "v_fmac_f32_dpp %[a2], %[m], %[e14] quad_perm:[1,0,3,2] row_mask:0xf bank_mask:0xf\n\t"
      "v_fmac_f32_dpp %[a2], %[m], %[e13] quad_perm:[2,3,0,1] row_mask:0xf bank_mask:0xf\n\t"
      "v_fmac_f32_dpp %[a2], %[m], %[e12] quad_perm:[3,2,1,0] row_mask:0xf bank_mask:0xf\n\t"
      "v_mul_f32 %[a3], %[c], %[e8]\n\t"
      "v_fmac_f32_dpp %[a3], %[c], %[e9] quad_perm:[1,0,3,2] row_mask:0xf bank_mask:0xf\n\t"
      "v_fmac_f32_dpp %[a3], %[c], %[e10] quad_perm:[2,3,0,1] row_mask:0xf bank_mask:0xf\n\t"
      "v_fmac_f32_dpp %[a3], %[c], %[e11] quad_perm:[3,2,1,0] row_mask:0xf bank_mask:0xf\n\t"
      "v_add_f32 %[gn], %[gn], %[a1]\n\t"
      "v_add_f32 %[a2], %[a2], %[a3]\n\t"
      "v_add_f32 %[gn], %[gn], %[a2]\n\t"
      "v_mul_f32 %[gn], %[gn], %[pe]"
      : [gn] "=&v"(gn), [h] "=&v"(h), [m] "=&v"(m), [c] "=&v"(c),
        [a1] "=&v"(a1), [a2] "=&v"(a2), [a3] "=&v"(a3)
      : [g] "v"(g), [pe] "v"(pe),
        [e0] "v"(E[0]), [e1] "v"(E[1]), [e2] "v"(E[2]), [e3] "v"(E[3]),
        [e4] "v"(E[4]), [e5] "v"(E[5]), [e6] "v"(E[6]), [e7] "v"(E[7]),
        [e8] "v"(E[8]), [e9] "v"(E[9]), [e10] "v"(E[10]), [e11] "v"(E[11]),
        [e12] "v"(E[12]), [e13] "v"(E[13]), [e14] "v"(E[14]), [e15] "v"(E[15]));
  return gn;
}

// ---------------------------------------------------------------------------
// Kernel 2: lens + CRF log-likelihood. One batch per block, 64 threads
// (4 redundant 16-lane rows). Steps s >= len are exact no-ops under the
// scaled-linear representation (g frozen, renorm folds into K2), so the scan
// runs a DYNAMIC trip count s = 1..len-1: full 16-step chunks (renorm after
// each; growth <= 2^90 < 2^127) + a <=15-step remainder. No per-step masks.
// lps has +1 pad row so chunk prefetch (row <= 512) never clamps.
// ---------------------------------------------------------------------------
__global__ __launch_bounds__(64) void crf_kernel(const int* __restrict__ text,
                                                 const int* __restrict__ tags,
                                                 const float* __restrict__ trans,
                                                 const float* __restrict__ probs,
                                                 float* __restrict__ out_lens,
                                                 float* __restrict__ out_ll) {
  __shared__ float lps[(SS + 1) * NT];  // probs * LOG2E, +1 pad row
  __shared__ int tgs[SS];
  __shared__ float trs[256];

  const int tid = threadIdx.x;
  const int j = tid & 15;
  const int b = blockIdx.x;

  // ---- stage (coalesced), pre-scaling probs by log2e ----
  {
    const float4* p4 = (const float4*)(probs + (size_t)b * SS * NT);
    float4* l4 = (float4*)lps;
#pragma unroll
    for (int i = 0; i < 32; ++i) {
      float4 v = p4[tid + 64 * i];
      v.x *= LOG2E; v.y *= LOG2E; v.z *= LOG2E; v.w *= LOG2E;
      l4[tid + 64 * i] = v;
    }
    const int4* t4 = (const int4*)(tags + b * SS);
    int4* lt = (int4*)tgs;
#pragma unroll
    for (int i = 0; i < 2; ++i) lt[tid + 64 * i] = t4[tid + 64 * i];
    for (int i = tid; i < 256; i += 64) trs[i] = trans[i];
  }
  __syncthreads();

  // ---- lens (fused) ----
  const int* tx = text + b * SS;
  int cnt = 0;
#pragma unroll
  for (int k = 0; k < 8; ++k) cnt += (tx[tid + 64 * k] != 0) ? 1 : 0;
  for (int off = 32; off > 0; off >>= 1) cnt += __shfl_xor(cnt, off, 64);
  const int len = cnt;
  if (tid == 0) out_lens[b] = (float)len;

  // ---- phase A: unary + binary scores ----
  float su = 0.f, sb = 0.f;
#pragma unroll
  for (int it = 0; it < 8; ++it) {
    const int s = tid + 64 * it;
    if (s < len) {
      int t1 = tgs[s];
      su += lps[s * NT + t1];
      if (s >= 1) sb += trs[tgs[s - 1] * 16 + t1];
    }
  }
  float sc = fmaf(su, LN2, sb);
  for (int off = 32; off > 0; off >>= 1) sc += __shfl_xor(sc, off, 64);

  // ---- E[k] = exp(trans[j^k, j]) ----
  float E[16];
#pragma unroll
  for (int k = 0; k < 16; ++k) E[k] = __expf(trs[((j ^ k) << 4) + j]);

  // ---- scan: s = 1 .. len-1 ----
  float g = exp2f(lps[j]);  // alpha from step 0
  float K2 = 0.f;

  const int T = (len > 0) ? len - 1 : 0;  // number of scan steps
  const int nfull = T >> 4;
  const int rem = T & 15;

  float raw[16];
#pragma unroll
  for (int c = 0; c < 16; ++c) raw[c] = lps[(1 + c) * NT + j];

  int s0 = 1;
  for (int blk = 0; blk < nfull; ++blk) {
#pragma unroll
    for (int c = 0; c < 16; ++c) {
      float pe = exp2f(raw[c]);
      raw[c] = lps[(s0 + 16 + c) * NT + j];  // rows <= 512 (pad row)
      g = crf_step(g, pe, E);
    }
    // renorm every 16 steps; exact fold into K2
    float mx = g;
    mx = fmaxf(mx, dppmov<0xB1>(mx));
    mx = fmaxf(mx, dppmov<0x4E>(mx));
    mx = fmaxf(mx, dppmov<0x141>(mx));
    mx = fmaxf(mx, dppmov<0x140>(mx));
    float rr = 1.0f / mx;
    K2 -= __log2f(rr);
    g *= rr;
    s0 += 16;
  }
  for (int c = 0; c < rem; ++c) {
    float pe = exp2f(raw[c]);
    g = crf_step(g, pe, E);
  }

  // ---- final logsumexp across the 16 alphas ----
  float x = g;
  x += dppmov<0xB1>(x);
  x += dppmov<0x4E>(x);
  x += dppmov<0x141>(x);
  x += dppmov<0x140>(x);
  float log_norm = LN2 * (K2 + __log2f(x));
  if (tid == 0) out_ll[b] = sc - log_norm;
}

// ---------------------------------------------------------------------------
extern "C" void kernel_launch(void* const* d_in, const int* in_sizes, int n_in,
                              void* d_out, int out_size, void* d_ws, size_t ws_size,
                              hipStream_t stream) {
  const int* text = (const int*)d_in[0];
  const int* tags = (const int*)d_in[1];
  const float* emb = (const float*)d_in[2];
  const float* W = (const float*)d_in[3];
  const float* bias = (const float*)d_in[4];
  const float* trans = (const float*)d_in[5];

  float* out = (float*)d_out;
  float* out_probs = out;                   // 64*512*16
  float* out_lens = out + BB * SS * NT;     // 64
  float* out_ll = out + BB * SS * NT + BB;  // 64

  probs_kernel<<<(BB * SS) / 16, 256, 0, stream>>>(text, emb, W, bias, out_probs);
  crf_kernel<<<BB, 64, 0, stream>>>(text, tags, trans, out_probs, out_lens, out_ll);
}